// Round 3
// baseline (2082.655 us; speedup 1.0000x reference)
//
#include <hip/hip_runtime.h>
#include <hip/hip_bf16.h>

#define N_NODES 100000
#define EMB 256
#define N_MP 1600000
#define N_SUP 200000

__device__ __forceinline__ int clampi(int v, int lo, int hi) {
    return v < lo ? lo : (v > hi ? hi : v);
}

// ---------------- CSR build ----------------

__global__ void hist_kernel(const int* __restrict__ dst, int n, int* __restrict__ hist) {
    int i = blockIdx.x * 256 + threadIdx.x;
    if (i < n) atomicAdd(&hist[clampi(dst[i], 0, N_NODES - 1)], 1);
}

// single-block exclusive scan over n elements -> rp[0..n]
__global__ void scan_kernel(const int* __restrict__ hist, int* __restrict__ rp, int n) {
    __shared__ int lds[1024];
    __shared__ int carry;
    if (threadIdx.x == 0) carry = 0;
    __syncthreads();
    for (int base = 0; base < n; base += 1024) {
        int i = base + (int)threadIdx.x;
        int v = (i < n) ? hist[i] : 0;
        lds[threadIdx.x] = v;
        __syncthreads();
        for (int off = 1; off < 1024; off <<= 1) {
            int t = (threadIdx.x >= (unsigned)off) ? lds[threadIdx.x - off] : 0;
            __syncthreads();
            lds[threadIdx.x] += t;
            __syncthreads();
        }
        int inc = lds[threadIdx.x];
        if (i < n) rp[i + 1] = carry + inc;
        __syncthreads();
        if (threadIdx.x == 1023) carry += lds[1023];
        __syncthreads();
    }
    if (threadIdx.x == 0) rp[0] = 0;
}

__global__ void scatter_kernel(const int* __restrict__ src, const int* __restrict__ dst, int n,
                               const int* __restrict__ rp, int* __restrict__ fill,
                               int* __restrict__ srt) {
    int i = blockIdx.x * 256 + threadIdx.x;
    if (i < n) {
        int d = clampi(dst[i], 0, N_NODES - 1);
        int pos = rp[d] + atomicAdd(&fill[d], 1);
        if (pos >= 0 && pos < n) srt[pos] = clampi(src[i], 0, N_NODES - 1);
    }
}

// ---------------- mean aggregation: wave per node ----------------

__global__ void agg_kernel(const float* __restrict__ x, const int* __restrict__ rp,
                           const int* __restrict__ srt, float* __restrict__ outm) {
    int w = threadIdx.x >> 6;
    int lane = threadIdx.x & 63;
    int node = blockIdx.x * 4 + w;
    if (node >= N_NODES) return;
    int beg = rp[node], end = rp[node + 1];
    float4 acc = make_float4(0.f, 0.f, 0.f, 0.f);
    for (int e = beg; e < end; ++e) {
        int s = clampi(srt[e], 0, N_NODES - 1);
        float4 v = *(const float4*)&x[s * EMB + lane * 4];
        acc.x += v.x; acc.y += v.y; acc.z += v.z; acc.w += v.w;
    }
    float inv = 1.0f / fmaxf((float)(end - beg), 1.0f);
    float4 o = make_float4(acc.x * inv, acc.y * inv, acc.z * inv, acc.w * inv);
    *(float4*)&outm[node * EMB + lane * 4] = o;
}

// ---------------- fused GEMM: out = Am@Wl^T + Ax@Wr^T + b (opt relu) ----------------
// BM=128, BN=128, BK=16, 256 threads, 8x8 micro-tile per thread.

#define BM 128
#define BN 128
#define BK 16

__global__ __launch_bounds__(256) void gemm_kernel(
    const float* __restrict__ Am, const float* __restrict__ Ax,
    const float* __restrict__ Wl, const float* __restrict__ Wr,
    const float* __restrict__ bias, float* __restrict__ out, int M, int do_relu) {
    __shared__ float As[BK][BM + 4];
    __shared__ float Bs[BK][BN + 4];
    int tid = threadIdx.x;
    int m0 = blockIdx.x * BM;
    int n0 = blockIdx.y * BN;
    int tx = tid & 15;        // n dir
    int ty = tid >> 4;        // m dir
    int ar = tid >> 2;        // 0..63 (tile row for loads)
    int ac = (tid & 3) * 4;   // 0,4,8,12 (k col group)

    float acc[8][8];
#pragma unroll
    for (int i = 0; i < 8; ++i)
#pragma unroll
        for (int j = 0; j < 8; ++j) acc[i][j] = 0.f;

#pragma unroll
    for (int phase = 0; phase < 2; ++phase) {
        const float* A = phase ? Ax : Am;
        const float* W = phase ? Wr : Wl;
        for (int k0 = 0; k0 < EMB; k0 += BK) {
            // load A tile (transposed to As[k][m])
#pragma unroll
            for (int h = 0; h < 2; ++h) {
                int row = m0 + ar + h * 64;
                float4 v = make_float4(0.f, 0.f, 0.f, 0.f);
                if (row < M) v = *(const float4*)&A[row * EMB + k0 + ac];
                As[ac + 0][ar + h * 64] = v.x;
                As[ac + 1][ar + h * 64] = v.y;
                As[ac + 2][ar + h * 64] = v.z;
                As[ac + 3][ar + h * 64] = v.w;
            }
            // load B tile: Bs[k][n] = W[n0+n][k0+k]
#pragma unroll
            for (int h = 0; h < 2; ++h) {
                int nrow = n0 + ar + h * 64;
                float4 v = *(const float4*)&W[nrow * EMB + k0 + ac];
                Bs[ac + 0][ar + h * 64] = v.x;
                Bs[ac + 1][ar + h * 64] = v.y;
                Bs[ac + 2][ar + h * 64] = v.z;
                Bs[ac + 3][ar + h * 64] = v.w;
            }
            __syncthreads();
#pragma unroll
            for (int k = 0; k < BK; ++k) {
                float a[8], b[8];
                *(float4*)&a[0] = *(float4*)&As[k][ty * 4];
                *(float4*)&a[4] = *(float4*)&As[k][64 + ty * 4];
                *(float4*)&b[0] = *(float4*)&Bs[k][tx * 4];
                *(float4*)&b[4] = *(float4*)&Bs[k][64 + tx * 4];
#pragma unroll
                for (int i = 0; i < 8; ++i)
#pragma unroll
                    for (int j = 0; j < 8; ++j) acc[i][j] += a[i] * b[j];
            }
            __syncthreads();
        }
    }

    // epilogue: bias + optional relu
#pragma unroll
    for (int i = 0; i < 8; ++i) {
        int row = m0 + ((i < 4) ? (ty * 4 + i) : (64 + ty * 4 + (i - 4)));
        if (row < M) {
#pragma unroll
            for (int jh = 0; jh < 2; ++jh) {
                int col = n0 + jh * 64 + tx * 4;
                float4 o;
                o.x = acc[i][jh * 4 + 0] + bias[col + 0];
                o.y = acc[i][jh * 4 + 1] + bias[col + 1];
                o.z = acc[i][jh * 4 + 2] + bias[col + 2];
                o.w = acc[i][jh * 4 + 3] + bias[col + 3];
                if (do_relu) {
                    o.x = fmaxf(o.x, 0.f); o.y = fmaxf(o.y, 0.f);
                    o.z = fmaxf(o.z, 0.f); o.w = fmaxf(o.w, 0.f);
                }
                *(float4*)&out[row * EMB + col] = o;
            }
        }
    }
}

// ---------------- supervision scores: wave per edge ----------------

__global__ void score_kernel(const float* __restrict__ x, const int* __restrict__ sup,
                             float* __restrict__ out) {
    int w = threadIdx.x >> 6;
    int lane = threadIdx.x & 63;
    int e = blockIdx.x * 4 + w;
    if (e >= N_SUP) return;
    int s = clampi(sup[e], 0, N_NODES - 1);
    int d = clampi(sup[N_SUP + e], 0, N_NODES - 1);
    float4 a = *(const float4*)&x[s * EMB + lane * 4];
    float4 b = *(const float4*)&x[d * EMB + lane * 4];
    float t = a.x * b.x + a.y * b.y + a.z * b.z + a.w * b.w;
#pragma unroll
    for (int off = 32; off > 0; off >>= 1) t += __shfl_down(t, off, 64);
    if (lane == 0) out[e] = t;
}

// ---------------- launch ----------------

extern "C" void kernel_launch(void* const* d_in, const int* in_sizes, int n_in,
                              void* d_out, int out_size, void* d_ws, size_t ws_size,
                              hipStream_t stream) {
    const float* x0  = (const float*)d_in[0];
    const int*   mp  = (const int*)d_in[1];
    const int*   sup = (const int*)d_in[2];
    const float* Wl1 = (const float*)d_in[3];
    const float* bl1 = (const float*)d_in[4];
    const float* Wr1 = (const float*)d_in[5];
    const float* Wl2 = (const float*)d_in[6];
    const float* bl2 = (const float*)d_in[7];
    const float* Wr2 = (const float*)d_in[8];
    const float* Wl3 = (const float*)d_in[9];
    const float* bl3 = (const float*)d_in[10];
    const float* Wr3 = (const float*)d_in[11];
    float* scores = (float*)d_out;

    const int* mp_src = mp;
    const int* mp_dst = mp + N_MP;

    char* base = (char*)d_ws;
    size_t off = 0;
    auto alloc = [&](size_t bytes) {
        void* p = base + off;
        off = (off + bytes + 255) & ~(size_t)255;
        return p;
    };
    int* rp   = (int*)alloc((N_NODES + 1) * sizeof(int));
    int* hist = (int*)alloc(N_NODES * sizeof(int));
    int* fill = (int*)alloc(N_NODES * sizeof(int));
    int* srt  = (int*)alloc(N_MP * sizeof(int));
    float* bufA = (float*)alloc((size_t)N_NODES * EMB * sizeof(float));
    float* bufB = (float*)alloc((size_t)N_NODES * EMB * sizeof(float));
    float* bufC = (float*)alloc((size_t)N_NODES * EMB * sizeof(float));
    (void)ws_size; (void)n_in; (void)in_sizes; (void)out_size;

    hipMemsetAsync(hist, 0, N_NODES * sizeof(int), stream);
    hipMemsetAsync(fill, 0, N_NODES * sizeof(int), stream);

    // CSR build
    hist_kernel<<<(N_MP + 255) / 256, 256, 0, stream>>>(mp_dst, N_MP, hist);
    scan_kernel<<<1, 1024, 0, stream>>>(hist, rp, N_NODES);
    scatter_kernel<<<(N_MP + 255) / 256, 256, 0, stream>>>(mp_src, mp_dst, N_MP, rp, fill, srt);

    dim3 gemm_grid((N_NODES + BM - 1) / BM, EMB / BN);
    int agg_blocks = (N_NODES + 3) / 4;

    // layer 1: agg(x0)->C ; gemm(C, x0)->A, relu
    agg_kernel<<<agg_blocks, 256, 0, stream>>>(x0, rp, srt, bufC);
    gemm_kernel<<<gemm_grid, 256, 0, stream>>>(bufC, x0, Wl1, Wr1, bl1, bufA, N_NODES, 1);
    // layer 2: agg(A)->C ; gemm(C, A)->B, relu
    agg_kernel<<<agg_blocks, 256, 0, stream>>>(bufA, rp, srt, bufC);
    gemm_kernel<<<gemm_grid, 256, 0, stream>>>(bufC, bufA, Wl2, Wr2, bl2, bufB, N_NODES, 1);
    // layer 3: agg(B)->C ; gemm(C, B)->A, no relu
    agg_kernel<<<agg_blocks, 256, 0, stream>>>(bufB, rp, srt, bufC);
    gemm_kernel<<<gemm_grid, 256, 0, stream>>>(bufC, bufB, Wl3, Wr3, bl3, bufA, N_NODES, 0);

    // scores
    score_kernel<<<(N_SUP + 3) / 4, 256, 0, stream>>>(bufA, sup, scores);
}

// Round 4
// 1111.596 us; speedup vs baseline: 1.8736x; 1.8736x over previous
//
#include <hip/hip_runtime.h>
#include <hip/hip_bf16.h>

#define N_NODES 100000
#define EMB 256
#define N_MP 1600000
#define N_SUP 200000

typedef __attribute__((ext_vector_type(4))) float f32x4;
typedef __attribute__((ext_vector_type(8))) short s16x8;

__device__ __forceinline__ int clampi(int v, int lo, int hi) {
    return v < lo ? lo : (v > hi ? hi : v);
}
__device__ __forceinline__ ushort f2bf(float f) {
    unsigned u = __float_as_uint(f);
    u += 0x7fffu + ((u >> 16) & 1u);   // round-to-nearest-even
    return (ushort)(u >> 16);
}
__device__ __forceinline__ float bf2f(ushort h) {
    return __uint_as_float(((unsigned)h) << 16);
}

#define GLOAD_LDS16(gsrc, ldst)                                                   \
    __builtin_amdgcn_global_load_lds(                                             \
        (const __attribute__((address_space(1))) void*)(gsrc),                    \
        (__attribute__((address_space(3))) void*)(ldst), 16, 0, 0)

// ---------------- fp32 -> bf16 convert (8 elems/thread, exact multiple) ----------

__global__ void f2b_kernel(const float* __restrict__ in, ushort* __restrict__ out, int n8) {
    int i = blockIdx.x * 256 + threadIdx.x;
    if (i >= n8) return;
    const float4* p = (const float4*)(in + (size_t)i * 8);
    float4 a = p[0], b = p[1];
    ushort4 lo = make_ushort4(f2bf(a.x), f2bf(a.y), f2bf(a.z), f2bf(a.w));
    ushort4 hi = make_ushort4(f2bf(b.x), f2bf(b.y), f2bf(b.z), f2bf(b.w));
    ushort4* q = (ushort4*)(out + (size_t)i * 8);
    q[0] = lo; q[1] = hi;
}

// ---------------- CSR build ----------------

__global__ void hist_kernel(const int* __restrict__ dst, int n, int* __restrict__ hist) {
    int i = blockIdx.x * 256 + threadIdx.x;
    if (i < n) atomicAdd(&hist[clampi(dst[i], 0, N_NODES - 1)], 1);
}

__global__ void scan_kernel(const int* __restrict__ hist, int* __restrict__ rp, int n) {
    __shared__ int lds[1024];
    __shared__ int carry;
    if (threadIdx.x == 0) carry = 0;
    __syncthreads();
    for (int base = 0; base < n; base += 1024) {
        int i = base + (int)threadIdx.x;
        int v = (i < n) ? hist[i] : 0;
        lds[threadIdx.x] = v;
        __syncthreads();
        for (int off = 1; off < 1024; off <<= 1) {
            int t = (threadIdx.x >= (unsigned)off) ? lds[threadIdx.x - off] : 0;
            __syncthreads();
            lds[threadIdx.x] += t;
            __syncthreads();
        }
        int inc = lds[threadIdx.x];
        if (i < n) rp[i + 1] = carry + inc;
        __syncthreads();
        if (threadIdx.x == 1023) carry += lds[1023];
        __syncthreads();
    }
    if (threadIdx.x == 0) rp[0] = 0;
}

__global__ void scatter_kernel(const int* __restrict__ src, const int* __restrict__ dst, int n,
                               const int* __restrict__ rp, int* __restrict__ fill,
                               int* __restrict__ srt) {
    int i = blockIdx.x * 256 + threadIdx.x;
    if (i < n) {
        int d = clampi(dst[i], 0, N_NODES - 1);
        int pos = rp[d] + atomicAdd(&fill[d], 1);
        if (pos >= 0 && pos < n) srt[pos] = clampi(src[i], 0, N_NODES - 1);
    }
}

// ---------------- mean aggregation: wave per node, bf16 rows ----------------

__global__ void agg_kernel(const ushort* __restrict__ x, const int* __restrict__ rp,
                           const int* __restrict__ srt, ushort* __restrict__ outm) {
    int w = threadIdx.x >> 6;
    int lane = threadIdx.x & 63;
    int node = blockIdx.x * 4 + w;
    if (node >= N_NODES) return;
    int beg = rp[node], end = rp[node + 1];
    float ax = 0.f, ay = 0.f, az = 0.f, aw = 0.f;
    for (int e = beg; e < end; ++e) {
        int s = clampi(srt[e], 0, N_NODES - 1);
        ushort4 v = *(const ushort4*)&x[(size_t)s * EMB + lane * 4];
        ax += bf2f(v.x); ay += bf2f(v.y); az += bf2f(v.z); aw += bf2f(v.w);
    }
    float inv = 1.0f / fmaxf((float)(end - beg), 1.0f);
    ushort4 o = make_ushort4(f2bf(ax * inv), f2bf(ay * inv), f2bf(az * inv), f2bf(aw * inv));
    *(ushort4*)&outm[(size_t)node * EMB + lane * 4] = o;
}

// ---------------- bf16 MFMA GEMM: out = Am@Wl^T + Ax@Wr^T + b (opt relu) --------
// BM=BN=128, BK=64 (bf16). 4 waves, each owns a 64x64 quadrant (4x4 fragments of
// 16x16x32 MFMA). global_load_lds (16B) into LINEAR LDS; XOR swizzle applied on
// the GLOBAL source chunk and again on the ds_read side (same involution):
//   LDS[r][cc] = G[r][cc ^ (r&7)]  (16B chunks, 8 per 128B row)
// ds_read addr: chunk' = (ks*4 + (lane>>4)) ^ (r&7)  ->  conflict-free (<=2-way).

#define BM 128
#define BN 128
#define BKG 64

__global__ __launch_bounds__(256) void gemm_kernel(
    const ushort* __restrict__ Am, const ushort* __restrict__ Ax,
    const ushort* __restrict__ Wl, const ushort* __restrict__ Wr,
    const float* __restrict__ bias, ushort* __restrict__ out, int M, int do_relu) {
    __shared__ ushort As[BM * BKG];   // 16 KiB
    __shared__ ushort Bs[BN * BKG];   // 16 KiB
    const int tid = threadIdx.x;
    const int lane = tid & 63;
    const int w = tid >> 6;
    const int m0 = blockIdx.x * BM;
    const int n0 = blockIdx.y * BN;
    const int wr = w >> 1;
    const int wc = w & 1;

    f32x4 acc[4][4];
#pragma unroll
    for (int i = 0; i < 4; ++i)
#pragma unroll
        for (int j = 0; j < 4; ++j) acc[i][j] = (f32x4){0.f, 0.f, 0.f, 0.f};

    // staging: segment s = w*4+j (16 segments of 1KiB); chunk c = s*64+lane
    size_t srcA[4], srcB[4];
    int ldso[4];
#pragma unroll
    for (int j = 0; j < 4; ++j) {
        int c = (w * 4 + j) * 64 + lane;
        int r = c >> 3;                       // tile row 0..127
        int cc = (c & 7) ^ (r & 7);           // inverse-swizzled source chunk
        int arow = m0 + r; if (arow > M - 1) arow = M - 1;   // tail clamp (row-local GEMM)
        srcA[j] = (size_t)arow * EMB + cc * 8;
        srcB[j] = (size_t)(n0 + r) * EMB + cc * 8;
        ldso[j] = (w * 4 + j) * 512;          // ushort units (1KiB segments)
    }

#pragma unroll
    for (int phase = 0; phase < 2; ++phase) {
        const ushort* A = phase ? Ax : Am;
        const ushort* W = phase ? Wr : Wl;
        for (int k0 = 0; k0 < EMB; k0 += BKG) {
#pragma unroll
            for (int j = 0; j < 4; ++j) GLOAD_LDS16(A + srcA[j] + k0, As + ldso[j]);
#pragma unroll
            for (int j = 0; j < 4; ++j) GLOAD_LDS16(W + srcB[j] + k0, Bs + ldso[j]);
            asm volatile("s_waitcnt vmcnt(0)" ::: "memory");
            __syncthreads();
#pragma unroll
            for (int ks = 0; ks < 2; ++ks) {
                const int ccr = ((ks * 4 + (lane >> 4)) ^ (lane & 7)) * 8;
                s16x8 af[4], bg[4];
#pragma unroll
                for (int mf = 0; mf < 4; ++mf) {
                    int r = wr * 64 + mf * 16 + (lane & 15);
                    af[mf] = *(const s16x8*)&As[r * BKG + ccr];
                }
#pragma unroll
                for (int nf = 0; nf < 4; ++nf) {
                    int r = wc * 64 + nf * 16 + (lane & 15);
                    bg[nf] = *(const s16x8*)&Bs[r * BKG + ccr];
                }
#pragma unroll
                for (int mf = 0; mf < 4; ++mf)
#pragma unroll
                    for (int nf = 0; nf < 4; ++nf)
                        acc[mf][nf] = __builtin_amdgcn_mfma_f32_16x16x32_bf16(
                            af[mf], bg[nf], acc[mf][nf], 0, 0, 0);
            }
            __syncthreads();
        }
    }

    // epilogue: C/D mapping col=lane&15, row=(lane>>4)*4+q  [m89-verified]
#pragma unroll
    for (int nf = 0; nf < 4; ++nf) {
        int col = n0 + wc * 64 + nf * 16 + (lane & 15);
        float bv = bias[col];
#pragma unroll
        for (int mf = 0; mf < 4; ++mf) {
            int rbase = m0 + wr * 64 + mf * 16 + ((lane >> 4) << 2);
#pragma unroll
            for (int q = 0; q < 4; ++q) {
                int row = rbase + q;
                if (row < M) {
                    float v = acc[mf][nf][q] + bv;
                    if (do_relu) v = fmaxf(v, 0.f);
                    out[(size_t)row * EMB + col] = f2bf(v);
                }
            }
        }
    }
}

// ---------------- supervision scores: wave per edge, bf16 in fp32 acc -----------

__global__ void score_kernel(const ushort* __restrict__ x, const int* __restrict__ sup,
                             float* __restrict__ out) {
    int w = threadIdx.x >> 6;
    int lane = threadIdx.x & 63;
    int e = blockIdx.x * 4 + w;
    if (e >= N_SUP) return;
    int s = clampi(sup[e], 0, N_NODES - 1);
    int d = clampi(sup[N_SUP + e], 0, N_NODES - 1);
    ushort4 a = *(const ushort4*)&x[(size_t)s * EMB + lane * 4];
    ushort4 b = *(const ushort4*)&x[(size_t)d * EMB + lane * 4];
    float t = bf2f(a.x) * bf2f(b.x) + bf2f(a.y) * bf2f(b.y) +
              bf2f(a.z) * bf2f(b.z) + bf2f(a.w) * bf2f(b.w);
#pragma unroll
    for (int off = 32; off > 0; off >>= 1) t += __shfl_down(t, off, 64);
    if (lane == 0) out[e] = t;
}

// ---------------- launch ----------------

extern "C" void kernel_launch(void* const* d_in, const int* in_sizes, int n_in,
                              void* d_out, int out_size, void* d_ws, size_t ws_size,
                              hipStream_t stream) {
    const float* x0  = (const float*)d_in[0];
    const int*   mp  = (const int*)d_in[1];
    const int*   sup = (const int*)d_in[2];
    const float* Wf[6] = {(const float*)d_in[3], (const float*)d_in[5],
                          (const float*)d_in[6], (const float*)d_in[8],
                          (const float*)d_in[9], (const float*)d_in[11]};
    const float* bl1 = (const float*)d_in[4];
    const float* bl2 = (const float*)d_in[7];
    const float* bl3 = (const float*)d_in[10];
    float* scores = (float*)d_out;

    const int* mp_src = mp;
    const int* mp_dst = mp + N_MP;

    char* base = (char*)d_ws;
    size_t off = 0;
    auto alloc = [&](size_t bytes) {
        void* p = base + off;
        off = (off + bytes + 255) & ~(size_t)255;
        return p;
    };
    int* rp   = (int*)alloc((N_NODES + 1) * sizeof(int));
    int* hist = (int*)alloc(N_NODES * sizeof(int));
    int* fill = (int*)alloc(N_NODES * sizeof(int));
    int* srt  = (int*)alloc(N_MP * sizeof(int));
    ushort* x0b  = (ushort*)alloc((size_t)N_NODES * EMB * sizeof(ushort));
    ushort* bufA = (ushort*)alloc((size_t)N_NODES * EMB * sizeof(ushort));
    ushort* bufB = (ushort*)alloc((size_t)N_NODES * EMB * sizeof(ushort));
    ushort* bufC = (ushort*)alloc((size_t)N_NODES * EMB * sizeof(ushort));
    ushort* Wb[6];
    for (int i = 0; i < 6; ++i) Wb[i] = (ushort*)alloc((size_t)EMB * EMB * sizeof(ushort));
    (void)ws_size; (void)n_in; (void)in_sizes; (void)out_size;

    hipMemsetAsync(hist, 0, N_NODES * sizeof(int), stream);
    hipMemsetAsync(fill, 0, N_NODES * sizeof(int), stream);

    // convert inputs to bf16
    f2b_kernel<<<(N_NODES * EMB / 8 + 255) / 256, 256, 0, stream>>>(x0, x0b, N_NODES * EMB / 8);
    for (int i = 0; i < 6; ++i)
        f2b_kernel<<<(EMB * EMB / 8 + 255) / 256, 256, 0, stream>>>(Wf[i], Wb[i], EMB * EMB / 8);

    // CSR build
    hist_kernel<<<(N_MP + 255) / 256, 256, 0, stream>>>(mp_dst, N_MP, hist);
    scan_kernel<<<1, 1024, 0, stream>>>(hist, rp, N_NODES);
    scatter_kernel<<<(N_MP + 255) / 256, 256, 0, stream>>>(mp_src, mp_dst, N_MP, rp, fill, srt);

    dim3 gemm_grid((N_NODES + BM - 1) / BM, EMB / BN);
    int agg_blocks = (N_NODES + 3) / 4;

    // Wb order: 0=Wl1 1=Wr1 2=Wl2 3=Wr2 4=Wl3 5=Wr3
    agg_kernel<<<agg_blocks, 256, 0, stream>>>(x0b, rp, srt, bufC);
    gemm_kernel<<<gemm_grid, 256, 0, stream>>>(bufC, x0b, Wb[0], Wb[1], bl1, bufA, N_NODES, 1);

    agg_kernel<<<agg_blocks, 256, 0, stream>>>(bufA, rp, srt, bufC);
    gemm_kernel<<<gemm_grid, 256, 0, stream>>>(bufC, bufA, Wb[2], Wb[3], bl2, bufB, N_NODES, 1);

    agg_kernel<<<agg_blocks, 256, 0, stream>>>(bufB, rp, srt, bufC);
    gemm_kernel<<<gemm_grid, 256, 0, stream>>>(bufC, bufB, Wb[4], Wb[5], bl3, bufA, N_NODES, 0);

    score_kernel<<<(N_SUP + 3) / 4, 256, 0, stream>>>(bufA, sup, scores);
}

// Round 5
// 815.046 us; speedup vs baseline: 2.5553x; 1.3638x over previous
//
#include <hip/hip_runtime.h>
#include <hip/hip_bf16.h>

#define N_NODES 100000
#define EMB 256
#define N_MP 1600000
#define N_SUP 200000

typedef __attribute__((ext_vector_type(4))) float f32x4;
typedef __attribute__((ext_vector_type(8))) short s16x8;

__device__ __forceinline__ int clampi(int v, int lo, int hi) {
    return v < lo ? lo : (v > hi ? hi : v);
}
__device__ __forceinline__ ushort f2bf(float f) {
    unsigned u = __float_as_uint(f);
    u += 0x7fffu + ((u >> 16) & 1u);   // round-to-nearest-even
    return (ushort)(u >> 16);
}
__device__ __forceinline__ float bf2f(ushort h) {
    return __uint_as_float(((unsigned)h) << 16);
}

#define GLOAD_LDS16(gsrc, ldst)                                                   \
    __builtin_amdgcn_global_load_lds(                                             \
        (const __attribute__((address_space(1))) void*)(gsrc),                    \
        (__attribute__((address_space(3))) void*)(ldst), 16, 0, 0)

// ---------------- fp32 -> bf16 convert ----------------

__global__ void f2b_kernel(const float* __restrict__ in, ushort* __restrict__ out, int n8) {
    int i = blockIdx.x * 256 + threadIdx.x;
    if (i >= n8) return;
    const float4* p = (const float4*)(in + (size_t)i * 8);
    float4 a = p[0], b = p[1];
    ushort4 lo = make_ushort4(f2bf(a.x), f2bf(a.y), f2bf(a.z), f2bf(a.w));
    ushort4 hi = make_ushort4(f2bf(b.x), f2bf(b.y), f2bf(b.z), f2bf(b.w));
    ushort4* q = (ushort4*)(out + (size_t)i * 8);
    q[0] = lo; q[1] = hi;
}

// ---------------- CSR build ----------------

__global__ void hist_kernel(const int* __restrict__ dst, int n, int* __restrict__ hist) {
    int i = blockIdx.x * 256 + threadIdx.x;
    if (i < n) atomicAdd(&hist[clampi(dst[i], 0, N_NODES - 1)], 1);
}

// ---- 3-kernel device-wide exclusive scan: hist[0..n) -> rp[0..n], rp[0]=0 ----
#define SCAN_CHUNK 1024
#define NB_SCAN ((N_NODES + SCAN_CHUNK - 1) / SCAN_CHUNK)   // 98

__global__ void scan_partial_kernel(const int* __restrict__ hist, int* __restrict__ psum, int n) {
    __shared__ int lds[4];
    int b = blockIdx.x;
    int tid = threadIdx.x, lane = tid & 63, wv = tid >> 6;
    int base = b * SCAN_CHUNK + tid * 4;
    int s = 0;
    if (base + 3 < n) {
        int4 v = *(const int4*)&hist[base];
        s = v.x + v.y + v.z + v.w;
    } else {
#pragma unroll
        for (int k = 0; k < 4; ++k) { int i = base + k; if (i < n) s += hist[i]; }
    }
#pragma unroll
    for (int off = 32; off; off >>= 1) s += __shfl_down(s, off, 64);
    if (lane == 0) lds[wv] = s;
    __syncthreads();
    if (tid == 0) psum[b] = lds[0] + lds[1] + lds[2] + lds[3];
}

__global__ void scan_blocksums_kernel(int* __restrict__ psum, int nb) {
    __shared__ int lds[128];
    int t = threadIdx.x;
    lds[t] = (t < nb) ? psum[t] : 0;
    __syncthreads();
    if (t == 0) {
        int run = 0;
        for (int i = 0; i < nb; ++i) { int v = lds[i]; lds[i] = run; run += v; }
    }
    __syncthreads();
    if (t < nb) psum[t] = lds[t];   // exclusive block offsets
}

__global__ void scan_final_kernel(const int* __restrict__ hist, const int* __restrict__ poff,
                                  int* __restrict__ rp, int n) {
    __shared__ int wsum[4];
    int b = blockIdx.x;
    int tid = threadIdx.x, lane = tid & 63, wv = tid >> 6;
    int base = b * SCAN_CHUNK + tid * 4;
    int v0 = 0, v1 = 0, v2 = 0, v3 = 0;
    if (base + 3 < n) {
        int4 v = *(const int4*)&hist[base];
        v0 = v.x; v1 = v.y; v2 = v.z; v3 = v.w;
    } else {
        if (base + 0 < n) v0 = hist[base + 0];
        if (base + 1 < n) v1 = hist[base + 1];
        if (base + 2 < n) v2 = hist[base + 2];
        if (base + 3 < n) v3 = hist[base + 3];
    }
    int s1 = v0 + v1, s2 = s1 + v2, s3 = s2 + v3;
    int t = s3;
#pragma unroll
    for (int off = 1; off < 64; off <<= 1) {
        int u = __shfl_up(t, off, 64);
        if (lane >= off) t += u;
    }
    if (lane == 63) wsum[wv] = t;
    __syncthreads();
    int woff = 0;
    for (int i = 0; i < wv; ++i) woff += wsum[i];
    int off0 = poff[b] + woff + (t - s3);    // exclusive offset of this thread
    if (base + 0 < n) rp[base + 1] = off0 + v0;
    if (base + 1 < n) rp[base + 2] = off0 + s1;
    if (base + 2 < n) rp[base + 3] = off0 + s2;
    if (base + 3 < n) rp[base + 4] = off0 + s3;
    if (b == 0 && tid == 0) rp[0] = 0;
}

__global__ void scatter_kernel(const int* __restrict__ src, const int* __restrict__ dst, int n,
                               const int* __restrict__ rp, int* __restrict__ fill,
                               int* __restrict__ srt) {
    int i = blockIdx.x * 256 + threadIdx.x;
    if (i < n) {
        int d = clampi(dst[i], 0, N_NODES - 1);
        int pos = rp[d] + atomicAdd(&fill[d], 1);
        if (pos >= 0 && pos < n) srt[pos] = clampi(src[i], 0, N_NODES - 1);
    }
}

// ---------------- mean aggregation: wave per node, shfl-broadcast indices -------

__global__ void agg_kernel(const ushort* __restrict__ x, const int* __restrict__ rp,
                           const int* __restrict__ srt, ushort* __restrict__ outm) {
    int w = threadIdx.x >> 6;
    int lane = threadIdx.x & 63;
    int node = blockIdx.x * 4 + w;
    if (node >= N_NODES) return;
    int beg = rp[node], end = rp[node + 1];
    int deg = end - beg;
    float ax = 0.f, ay = 0.f, az = 0.f, aw = 0.f;
    for (int bse = 0; bse < deg; bse += 64) {
        int rem = deg - bse;
        int cnt = rem < 64 ? rem : 64;
        int myidx = (lane < cnt) ? srt[beg + bse + lane] : 0;
        for (int j = 0; j < cnt; ++j) {
            int s = __shfl(myidx, j, 64);
            ushort4 v = *(const ushort4*)&x[(size_t)s * EMB + lane * 4];
            ax += bf2f(v.x); ay += bf2f(v.y); az += bf2f(v.z); aw += bf2f(v.w);
        }
    }
    float inv = 1.0f / fmaxf((float)deg, 1.0f);
    ushort4 o = make_ushort4(f2bf(ax * inv), f2bf(ay * inv), f2bf(az * inv), f2bf(aw * inv));
    *(ushort4*)&outm[(size_t)node * EMB + lane * 4] = o;
}

// ---------------- bf16 MFMA GEMM: out = Am@Wl^T + Ax@Wr^T + b (opt relu) --------

#define BM 128
#define BN 128
#define BKG 64

__global__ __launch_bounds__(256) void gemm_kernel(
    const ushort* __restrict__ Am, const ushort* __restrict__ Ax,
    const ushort* __restrict__ Wl, const ushort* __restrict__ Wr,
    const float* __restrict__ bias, ushort* __restrict__ out, int M, int do_relu) {
    __shared__ ushort As[BM * BKG];   // 16 KiB
    __shared__ ushort Bs[BN * BKG];   // 16 KiB
    const int tid = threadIdx.x;
    const int lane = tid & 63;
    const int w = tid >> 6;
    const int m0 = blockIdx.x * BM;
    const int n0 = blockIdx.y * BN;
    const int wr = w >> 1;
    const int wc = w & 1;

    f32x4 acc[4][4];
#pragma unroll
    for (int i = 0; i < 4; ++i)
#pragma unroll
        for (int j = 0; j < 4; ++j) acc[i][j] = (f32x4){0.f, 0.f, 0.f, 0.f};

    size_t srcA[4], srcB[4];
    int ldso[4];
#pragma unroll
    for (int j = 0; j < 4; ++j) {
        int c = (w * 4 + j) * 64 + lane;
        int r = c >> 3;
        int cc = (c & 7) ^ (r & 7);
        int arow = m0 + r; if (arow > M - 1) arow = M - 1;
        srcA[j] = (size_t)arow * EMB + cc * 8;
        srcB[j] = (size_t)(n0 + r) * EMB + cc * 8;
        ldso[j] = (w * 4 + j) * 512;
    }

#pragma unroll
    for (int phase = 0; phase < 2; ++phase) {
        const ushort* A = phase ? Ax : Am;
        const ushort* W = phase ? Wr : Wl;
        for (int k0 = 0; k0 < EMB; k0 += BKG) {
#pragma unroll
            for (int j = 0; j < 4; ++j) GLOAD_LDS16(A + srcA[j] + k0, As + ldso[j]);
#pragma unroll
            for (int j = 0; j < 4; ++j) GLOAD_LDS16(W + srcB[j] + k0, Bs + ldso[j]);
            asm volatile("s_waitcnt vmcnt(0)" ::: "memory");
            __syncthreads();
#pragma unroll
            for (int ks = 0; ks < 2; ++ks) {
                const int ccr = ((ks * 4 + (lane >> 4)) ^ (lane & 7)) * 8;
                s16x8 af[4], bg[4];
#pragma unroll
                for (int mf = 0; mf < 4; ++mf) {
                    int r = wr * 64 + mf * 16 + (lane & 15);
                    af[mf] = *(const s16x8*)&As[r * BKG + ccr];
                }
#pragma unroll
                for (int nf = 0; nf < 4; ++nf) {
                    int r = wc * 64 + nf * 16 + (lane & 15);
                    bg[nf] = *(const s16x8*)&Bs[r * BKG + ccr];
                }
#pragma unroll
                for (int mf = 0; mf < 4; ++mf)
#pragma unroll
                    for (int nf = 0; nf < 4; ++nf)
                        acc[mf][nf] = __builtin_amdgcn_mfma_f32_16x16x32_bf16(
                            af[mf], bg[nf], acc[mf][nf], 0, 0, 0);
            }
            __syncthreads();
        }
    }

#pragma unroll
    for (int nf = 0; nf < 4; ++nf) {
        int col = n0 + wc * 64 + nf * 16 + (lane & 15);
        float bv = bias[col];
#pragma unroll
        for (int mf = 0; mf < 4; ++mf) {
            int rbase = m0 + wr * 64 + mf * 16 + ((lane >> 4) << 2);
#pragma unroll
            for (int q = 0; q < 4; ++q) {
                int row = rbase + q;
                if (row < M) {
                    float v = acc[mf][nf][q] + bv;
                    if (do_relu) v = fmaxf(v, 0.f);
                    out[(size_t)row * EMB + col] = f2bf(v);
                }
            }
        }
    }
}

// ---------------- supervision scores ----------------

__global__ void score_kernel(const ushort* __restrict__ x, const int* __restrict__ sup,
                             float* __restrict__ out) {
    int w = threadIdx.x >> 6;
    int lane = threadIdx.x & 63;
    int e = blockIdx.x * 4 + w;
    if (e >= N_SUP) return;
    int s = clampi(sup[e], 0, N_NODES - 1);
    int d = clampi(sup[N_SUP + e], 0, N_NODES - 1);
    ushort4 a = *(const ushort4*)&x[(size_t)s * EMB + lane * 4];
    ushort4 b = *(const ushort4*)&x[(size_t)d * EMB + lane * 4];
    float t = bf2f(a.x) * bf2f(b.x) + bf2f(a.y) * bf2f(b.y) +
              bf2f(a.z) * bf2f(b.z) + bf2f(a.w) * bf2f(b.w);
#pragma unroll
    for (int off = 32; off > 0; off >>= 1) t += __shfl_down(t, off, 64);
    if (lane == 0) out[e] = t;
}

// ---------------- launch ----------------

extern "C" void kernel_launch(void* const* d_in, const int* in_sizes, int n_in,
                              void* d_out, int out_size, void* d_ws, size_t ws_size,
                              hipStream_t stream) {
    const float* x0  = (const float*)d_in[0];
    const int*   mp  = (const int*)d_in[1];
    const int*   sup = (const int*)d_in[2];
    const float* Wf[6] = {(const float*)d_in[3], (const float*)d_in[5],
                          (const float*)d_in[6], (const float*)d_in[8],
                          (const float*)d_in[9], (const float*)d_in[11]};
    const float* bl1 = (const float*)d_in[4];
    const float* bl2 = (const float*)d_in[7];
    const float* bl3 = (const float*)d_in[10];
    float* scores = (float*)d_out;

    const int* mp_src = mp;
    const int* mp_dst = mp + N_MP;

    char* base = (char*)d_ws;
    size_t off = 0;
    auto alloc = [&](size_t bytes) {
        void* p = base + off;
        off = (off + bytes + 255) & ~(size_t)255;
        return p;
    };
    int* rp   = (int*)alloc((N_NODES + 1) * sizeof(int));
    int* hist = (int*)alloc(N_NODES * sizeof(int));
    int* fill = (int*)alloc(N_NODES * sizeof(int));
    int* psum = (int*)alloc(NB_SCAN * sizeof(int));
    int* srt  = (int*)alloc(N_MP * sizeof(int));
    ushort* x0b  = (ushort*)alloc((size_t)N_NODES * EMB * sizeof(ushort));
    ushort* bufA = (ushort*)alloc((size_t)N_NODES * EMB * sizeof(ushort));
    ushort* bufB = (ushort*)alloc((size_t)N_NODES * EMB * sizeof(ushort));
    ushort* bufC = (ushort*)alloc((size_t)N_NODES * EMB * sizeof(ushort));
    ushort* Wb[6];
    for (int i = 0; i < 6; ++i) Wb[i] = (ushort*)alloc((size_t)EMB * EMB * sizeof(ushort));
    (void)ws_size; (void)n_in; (void)in_sizes; (void)out_size;

    hipMemsetAsync(hist, 0, N_NODES * sizeof(int), stream);
    hipMemsetAsync(fill, 0, N_NODES * sizeof(int), stream);

    // convert inputs to bf16
    f2b_kernel<<<(N_NODES * EMB / 8 + 255) / 256, 256, 0, stream>>>(x0, x0b, N_NODES * EMB / 8);
    for (int i = 0; i < 6; ++i)
        f2b_kernel<<<(EMB * EMB / 8 + 255) / 256, 256, 0, stream>>>(Wf[i], Wb[i], EMB * EMB / 8);

    // CSR build
    hist_kernel<<<(N_MP + 255) / 256, 256, 0, stream>>>(mp_dst, N_MP, hist);
    scan_partial_kernel<<<NB_SCAN, 256, 0, stream>>>(hist, psum, N_NODES);
    scan_blocksums_kernel<<<1, 128, 0, stream>>>(psum, NB_SCAN);
    scan_final_kernel<<<NB_SCAN, 256, 0, stream>>>(hist, psum, rp, N_NODES);
    scatter_kernel<<<(N_MP + 255) / 256, 256, 0, stream>>>(mp_src, mp_dst, N_MP, rp, fill, srt);

    dim3 gemm_grid((N_NODES + BM - 1) / BM, EMB / BN);
    int agg_blocks = (N_NODES + 3) / 4;

    // Wb order: 0=Wl1 1=Wr1 2=Wl2 3=Wr2 4=Wl3 5=Wr3
    agg_kernel<<<agg_blocks, 256, 0, stream>>>(x0b, rp, srt, bufC);
    gemm_kernel<<<gemm_grid, 256, 0, stream>>>(bufC, x0b, Wb[0], Wb[1], bl1, bufA, N_NODES, 1);

    agg_kernel<<<agg_blocks, 256, 0, stream>>>(bufA, rp, srt, bufC);
    gemm_kernel<<<gemm_grid, 256, 0, stream>>>(bufC, bufA, Wb[2], Wb[3], bl2, bufB, N_NODES, 1);

    agg_kernel<<<agg_blocks, 256, 0, stream>>>(bufB, rp, srt, bufC);
    gemm_kernel<<<gemm_grid, 256, 0, stream>>>(bufC, bufB, Wb[4], Wb[5], bl3, bufA, N_NODES, 0);

    score_kernel<<<(N_SUP + 3) / 4, 256, 0, stream>>>(bufA, sup, scores);
}

// Round 6
// 774.504 us; speedup vs baseline: 2.6890x; 1.0523x over previous
//
#include <hip/hip_runtime.h>
#include <hip/hip_bf16.h>

#define N_NODES 100000
#define EMB 256
#define N_MP 1600000
#define N_SUP 200000

typedef __attribute__((ext_vector_type(4))) float f32x4;
typedef __attribute__((ext_vector_type(8))) short s16x8;

__device__ __forceinline__ int clampi(int v, int lo, int hi) {
    return v < lo ? lo : (v > hi ? hi : v);
}
__device__ __forceinline__ ushort f2bf(float f) {
    unsigned u = __float_as_uint(f);
    u += 0x7fffu + ((u >> 16) & 1u);   // round-to-nearest-even
    return (ushort)(u >> 16);
}
__device__ __forceinline__ float bf2f(ushort h) {
    return __uint_as_float(((unsigned)h) << 16);
}

#define GLOAD_LDS16(gsrc, ldst)                                                   \
    __builtin_amdgcn_global_load_lds(                                             \
        (const __attribute__((address_space(1))) void*)(gsrc),                    \
        (__attribute__((address_space(3))) void*)(ldst), 16, 0, 0)

// ---------------- fp32 -> bf16 convert ----------------

__global__ void f2b_kernel(const float* __restrict__ in, ushort* __restrict__ out, int n8) {
    int i = blockIdx.x * 256 + threadIdx.x;
    if (i >= n8) return;
    const float4* p = (const float4*)(in + (size_t)i * 8);
    float4 a = p[0], b = p[1];
    ushort4 lo = make_ushort4(f2bf(a.x), f2bf(a.y), f2bf(a.z), f2bf(a.w));
    ushort4 hi = make_ushort4(f2bf(b.x), f2bf(b.y), f2bf(b.z), f2bf(b.w));
    ushort4* q = (ushort4*)(out + (size_t)i * 8);
    q[0] = lo; q[1] = hi;
}

// ---------------- CSR build ----------------

__global__ void hist_kernel(const int* __restrict__ dst, int n, int* __restrict__ hist) {
    int i = blockIdx.x * 256 + threadIdx.x;
    if (i < n) atomicAdd(&hist[clampi(dst[i], 0, N_NODES - 1)], 1);
}

#define SCAN_CHUNK 1024
#define NB_SCAN ((N_NODES + SCAN_CHUNK - 1) / SCAN_CHUNK)   // 98

__global__ void scan_partial_kernel(const int* __restrict__ hist, int* __restrict__ psum, int n) {
    __shared__ int lds[4];
    int b = blockIdx.x;
    int tid = threadIdx.x, lane = tid & 63, wv = tid >> 6;
    int base = b * SCAN_CHUNK + tid * 4;
    int s = 0;
    if (base + 3 < n) {
        int4 v = *(const int4*)&hist[base];
        s = v.x + v.y + v.z + v.w;
    } else {
#pragma unroll
        for (int k = 0; k < 4; ++k) { int i = base + k; if (i < n) s += hist[i]; }
    }
#pragma unroll
    for (int off = 32; off; off >>= 1) s += __shfl_down(s, off, 64);
    if (lane == 0) lds[wv] = s;
    __syncthreads();
    if (tid == 0) psum[b] = lds[0] + lds[1] + lds[2] + lds[3];
}

__global__ void scan_blocksums_kernel(int* __restrict__ psum, int nb) {
    __shared__ int lds[128];
    int t = threadIdx.x;
    lds[t] = (t < nb) ? psum[t] : 0;
    __syncthreads();
    if (t == 0) {
        int run = 0;
        for (int i = 0; i < nb; ++i) { int v = lds[i]; lds[i] = run; run += v; }
    }
    __syncthreads();
    if (t < nb) psum[t] = lds[t];
}

__global__ void scan_final_kernel(const int* __restrict__ hist, const int* __restrict__ poff,
                                  int* __restrict__ rp, int n) {
    __shared__ int wsum[4];
    int b = blockIdx.x;
    int tid = threadIdx.x, lane = tid & 63, wv = tid >> 6;
    int base = b * SCAN_CHUNK + tid * 4;
    int v0 = 0, v1 = 0, v2 = 0, v3 = 0;
    if (base + 3 < n) {
        int4 v = *(const int4*)&hist[base];
        v0 = v.x; v1 = v.y; v2 = v.z; v3 = v.w;
    } else {
        if (base + 0 < n) v0 = hist[base + 0];
        if (base + 1 < n) v1 = hist[base + 1];
        if (base + 2 < n) v2 = hist[base + 2];
        if (base + 3 < n) v3 = hist[base + 3];
    }
    int s1 = v0 + v1, s2 = s1 + v2, s3 = s2 + v3;
    int t = s3;
#pragma unroll
    for (int off = 1; off < 64; off <<= 1) {
        int u = __shfl_up(t, off, 64);
        if (lane >= off) t += u;
    }
    if (lane == 63) wsum[wv] = t;
    __syncthreads();
    int woff = 0;
    for (int i = 0; i < wv; ++i) woff += wsum[i];
    int off0 = poff[b] + woff + (t - s3);
    if (base + 0 < n) rp[base + 1] = off0 + v0;
    if (base + 1 < n) rp[base + 2] = off0 + s1;
    if (base + 2 < n) rp[base + 3] = off0 + s2;
    if (base + 3 < n) rp[base + 4] = off0 + s3;
    if (b == 0 && tid == 0) rp[0] = 0;
}

__global__ void scatter_kernel(const int* __restrict__ src, const int* __restrict__ dst, int n,
                               const int* __restrict__ rp, int* __restrict__ fill,
                               int* __restrict__ srt) {
    int i = blockIdx.x * 256 + threadIdx.x;
    if (i < n) {
        int d = clampi(dst[i], 0, N_NODES - 1);
        int pos = rp[d] + atomicAdd(&fill[d], 1);
        if (pos >= 0 && pos < n) srt[pos] = clampi(src[i], 0, N_NODES - 1);
    }
}

// ------- mean aggregation v2: wave per node, 2 edges/iter, 16B per lane --------
// Halves of the wave (32 lanes) each own one edge per iteration; lane sl owns
// cols [sl*8, sl*8+8). Halves combined once at the end via shfl_xor(32).

__global__ void agg_kernel(const ushort* __restrict__ x, const int* __restrict__ rp,
                           const int* __restrict__ srt, ushort* __restrict__ outm) {
    int w = threadIdx.x >> 6;
    int lane = threadIdx.x & 63;
    int half = lane >> 5;
    int sl = lane & 31;
    int node = blockIdx.x * 4 + w;
    if (node >= N_NODES) return;
    int beg = rp[node], end = rp[node + 1];
    int deg = end - beg;
    float acc[8];
#pragma unroll
    for (int i = 0; i < 8; ++i) acc[i] = 0.f;

    for (int bse = 0; bse < deg; bse += 64) {
        int rem = deg - bse;
        int cnt = rem < 64 ? rem : 64;
        int myidx = (lane < cnt) ? srt[beg + bse + lane] : 0;
        for (int j = 0; j < cnt; j += 2) {
            int e = j + half;
            int s = __shfl(myidx, e & 63, 64);
            if (e < cnt) {
                s16x8 v = *(const s16x8*)&x[(unsigned)s * EMB + sl * 8];
#pragma unroll
                for (int i = 0; i < 8; ++i) acc[i] += bf2f((ushort)v[i]);
            }
        }
    }
    // combine halves
#pragma unroll
    for (int i = 0; i < 8; ++i) acc[i] += __shfl_xor(acc[i], 32, 64);
    float inv = 1.0f / fmaxf((float)deg, 1.0f);
    if (half == 0) {
        s16x8 o;
#pragma unroll
        for (int i = 0; i < 8; ++i) o[i] = (short)f2bf(acc[i] * inv);
        *(s16x8*)&outm[(size_t)node * EMB + sl * 8] = o;
    }
}

// ---------------- bf16 MFMA GEMM: out = Am@Wl^T + Ax@Wr^T + b (opt relu) --------

#define BM 128
#define BN 128
#define BKG 64

__global__ __launch_bounds__(256) void gemm_kernel(
    const ushort* __restrict__ Am, const ushort* __restrict__ Ax,
    const ushort* __restrict__ Wl, const ushort* __restrict__ Wr,
    const float* __restrict__ bias, ushort* __restrict__ out, int M, int do_relu) {
    __shared__ ushort As[BM * BKG];   // 16 KiB
    __shared__ ushort Bs[BN * BKG];   // 16 KiB
    const int tid = threadIdx.x;
    const int lane = tid & 63;
    const int w = tid >> 6;
    const int m0 = blockIdx.x * BM;
    const int n0 = blockIdx.y * BN;
    const int wr = w >> 1;
    const int wc = w & 1;

    f32x4 acc[4][4];
#pragma unroll
    for (int i = 0; i < 4; ++i)
#pragma unroll
        for (int j = 0; j < 4; ++j) acc[i][j] = (f32x4){0.f, 0.f, 0.f, 0.f};

    size_t srcA[4], srcB[4];
    int ldso[4];
#pragma unroll
    for (int j = 0; j < 4; ++j) {
        int c = (w * 4 + j) * 64 + lane;
        int r = c >> 3;
        int cc = (c & 7) ^ (r & 7);
        int arow = m0 + r; if (arow > M - 1) arow = M - 1;
        srcA[j] = (size_t)arow * EMB + cc * 8;
        srcB[j] = (size_t)(n0 + r) * EMB + cc * 8;
        ldso[j] = (w * 4 + j) * 512;
    }

#pragma unroll
    for (int phase = 0; phase < 2; ++phase) {
        const ushort* A = phase ? Ax : Am;
        const ushort* W = phase ? Wr : Wl;
        for (int k0 = 0; k0 < EMB; k0 += BKG) {
#pragma unroll
            for (int j = 0; j < 4; ++j) GLOAD_LDS16(A + srcA[j] + k0, As + ldso[j]);
#pragma unroll
            for (int j = 0; j < 4; ++j) GLOAD_LDS16(W + srcB[j] + k0, Bs + ldso[j]);
            asm volatile("s_waitcnt vmcnt(0)" ::: "memory");
            __syncthreads();
#pragma unroll
            for (int ks = 0; ks < 2; ++ks) {
                const int ccr = ((ks * 4 + (lane >> 4)) ^ (lane & 7)) * 8;
                s16x8 af[4], bg[4];
#pragma unroll
                for (int mf = 0; mf < 4; ++mf) {
                    int r = wr * 64 + mf * 16 + (lane & 15);
                    af[mf] = *(const s16x8*)&As[r * BKG + ccr];
                }
#pragma unroll
                for (int nf = 0; nf < 4; ++nf) {
                    int r = wc * 64 + nf * 16 + (lane & 15);
                    bg[nf] = *(const s16x8*)&Bs[r * BKG + ccr];
                }
#pragma unroll
                for (int mf = 0; mf < 4; ++mf)
#pragma unroll
                    for (int nf = 0; nf < 4; ++nf)
                        acc[mf][nf] = __builtin_amdgcn_mfma_f32_16x16x32_bf16(
                            af[mf], bg[nf], acc[mf][nf], 0, 0, 0);
            }
            __syncthreads();
        }
    }

#pragma unroll
    for (int nf = 0; nf < 4; ++nf) {
        int col = n0 + wc * 64 + nf * 16 + (lane & 15);
        float bv = bias[col];
#pragma unroll
        for (int mf = 0; mf < 4; ++mf) {
            int rbase = m0 + wr * 64 + mf * 16 + ((lane >> 4) << 2);
#pragma unroll
            for (int q = 0; q < 4; ++q) {
                int row = rbase + q;
                if (row < M) {
                    float v = acc[mf][nf][q] + bv;
                    if (do_relu) v = fmaxf(v, 0.f);
                    out[(size_t)row * EMB + col] = f2bf(v);
                }
            }
        }
    }
}

// ------- supervision scores v2: wave per edge, both rows in one 16B/lane load ---

__global__ void score_kernel(const ushort* __restrict__ x, const int* __restrict__ sup,
                             float* __restrict__ out) {
    int w = threadIdx.x >> 6;
    int lane = threadIdx.x & 63;
    int half = lane >> 5;
    int sl = lane & 31;
    int e = blockIdx.x * 4 + w;
    if (e >= N_SUP) return;
    int s = clampi(sup[e], 0, N_NODES - 1);
    int d = clampi(sup[N_SUP + e], 0, N_NODES - 1);
    int row = half ? d : s;
    uint4 raw = *(const uint4*)&x[(unsigned)row * EMB + sl * 8];
    uint4 pr;
    pr.x = __shfl_xor(raw.x, 32, 64);
    pr.y = __shfl_xor(raw.y, 32, 64);
    pr.z = __shfl_xor(raw.z, 32, 64);
    pr.w = __shfl_xor(raw.w, 32, 64);
    float t = 0.f;
    unsigned a[4] = {raw.x, raw.y, raw.z, raw.w};
    unsigned b[4] = {pr.x, pr.y, pr.z, pr.w};
#pragma unroll
    for (int i = 0; i < 4; ++i) {
        t += bf2f((ushort)(a[i] & 0xffff)) * bf2f((ushort)(b[i] & 0xffff));
        t += bf2f((ushort)(a[i] >> 16)) * bf2f((ushort)(b[i] >> 16));
    }
#pragma unroll
    for (int off = 16; off > 0; off >>= 1) t += __shfl_xor(t, off, 64);
    if (lane == 0) out[e] = t;
}

// ---------------- launch ----------------

extern "C" void kernel_launch(void* const* d_in, const int* in_sizes, int n_in,
                              void* d_out, int out_size, void* d_ws, size_t ws_size,
                              hipStream_t stream) {
    const float* x0  = (const float*)d_in[0];
    const int*   mp  = (const int*)d_in[1];
    const int*   sup = (const int*)d_in[2];
    const float* Wf[6] = {(const float*)d_in[3], (const float*)d_in[5],
                          (const float*)d_in[6], (const float*)d_in[8],
                          (const float*)d_in[9], (const float*)d_in[11]};
    const float* bl1 = (const float*)d_in[4];
    const float* bl2 = (const float*)d_in[7];
    const float* bl3 = (const float*)d_in[10];
    float* scores = (float*)d_out;

    const int* mp_src = mp;
    const int* mp_dst = mp + N_MP;

    char* base = (char*)d_ws;
    size_t off = 0;
    auto alloc = [&](size_t bytes) {
        void* p = base + off;
        off = (off + bytes + 255) & ~(size_t)255;
        return p;
    };
    int* rp   = (int*)alloc((N_NODES + 1) * sizeof(int));
    int* hist = (int*)alloc(N_NODES * sizeof(int));
    int* fill = (int*)alloc(N_NODES * sizeof(int));
    int* psum = (int*)alloc(NB_SCAN * sizeof(int));
    int* srt  = (int*)alloc(N_MP * sizeof(int));
    ushort* x0b  = (ushort*)alloc((size_t)N_NODES * EMB * sizeof(ushort));
    ushort* bufA = (ushort*)alloc((size_t)N_NODES * EMB * sizeof(ushort));
    ushort* bufB = (ushort*)alloc((size_t)N_NODES * EMB * sizeof(ushort));
    ushort* bufC = (ushort*)alloc((size_t)N_NODES * EMB * sizeof(ushort));
    ushort* Wb[6];
    for (int i = 0; i < 6; ++i) Wb[i] = (ushort*)alloc((size_t)EMB * EMB * sizeof(ushort));
    (void)ws_size; (void)n_in; (void)in_sizes; (void)out_size;

    hipMemsetAsync(hist, 0, N_NODES * sizeof(int), stream);
    hipMemsetAsync(fill, 0, N_NODES * sizeof(int), stream);

    f2b_kernel<<<(N_NODES * EMB / 8 + 255) / 256, 256, 0, stream>>>(x0, x0b, N_NODES * EMB / 8);
    for (int i = 0; i < 6; ++i)
        f2b_kernel<<<(EMB * EMB / 8 + 255) / 256, 256, 0, stream>>>(Wf[i], Wb[i], EMB * EMB / 8);

    hist_kernel<<<(N_MP + 255) / 256, 256, 0, stream>>>(mp_dst, N_MP, hist);
    scan_partial_kernel<<<NB_SCAN, 256, 0, stream>>>(hist, psum, N_NODES);
    scan_blocksums_kernel<<<1, 128, 0, stream>>>(psum, NB_SCAN);
    scan_final_kernel<<<NB_SCAN, 256, 0, stream>>>(hist, psum, rp, N_NODES);
    scatter_kernel<<<(N_MP + 255) / 256, 256, 0, stream>>>(mp_src, mp_dst, N_MP, rp, fill, srt);

    dim3 gemm_grid((N_NODES + BM - 1) / BM, EMB / BN);
    int agg_blocks = (N_NODES + 3) / 4;

    agg_kernel<<<agg_blocks, 256, 0, stream>>>(x0b, rp, srt, bufC);
    gemm_kernel<<<gemm_grid, 256, 0, stream>>>(bufC, x0b, Wb[0], Wb[1], bl1, bufA, N_NODES, 1);

    agg_kernel<<<agg_blocks, 256, 0, stream>>>(bufA, rp, srt, bufC);
    gemm_kernel<<<gemm_grid, 256, 0, stream>>>(bufC, bufA, Wb[2], Wb[3], bl2, bufB, N_NODES, 1);

    agg_kernel<<<agg_blocks, 256, 0, stream>>>(bufB, rp, srt, bufC);
    gemm_kernel<<<gemm_grid, 256, 0, stream>>>(bufC, bufB, Wb[4], Wb[5], bl3, bufA, N_NODES, 0);

    score_kernel<<<(N_SUP + 3) / 4, 256, 0, stream>>>(bufA, sup, scores);
}